// Round 18
// baseline (720.420 us; speedup 1.0000x reference)
//
#include <hip/hip_runtime.h>
#include <math.h>

#define NNODES 30000
#define NEDGES 480000
#define NC 32
#define NL 3
#define NH 64
#define NBASIS 8
#define NSPEC 5
#define INV_AVG 0.0625f   // 1 / AVG_NEIGH

typedef _Float16 half2v __attribute__((ext_vector_type(2)));
typedef _Float16 half4v __attribute__((ext_vector_type(4)));
typedef _Float16 half8v __attribute__((ext_vector_type(8)));
typedef float    float4v __attribute__((ext_vector_type(4)));
typedef unsigned int uint32;

__device__ __forceinline__ float silu_f(float x) {
    return x / (1.f + __expf(-x));
}
__device__ __forceinline__ float rdlane(float v, int k) {
    return __uint_as_float(__builtin_amdgcn_readlane(__float_as_uint(v), k));
}
__device__ __forceinline__ half2v u2h(uint32 u) {
    union { uint32 u; half2v h; } x; x.u = u; return x.h;
}

// wgt16 layout (gather-friendly, per 16-edge group g = gi>>4, el = gi&15):
//   f16 index = g*2560 + el*160 + pos(h)
//   pos(h) = 2h (h<64) | 2(h-64)+1 (64<=h<128) | h (h>=128)

// ---------------------------------------------------------------- CSR build
__global__ void count_kernel(const int* __restrict__ receivers, int* __restrict__ deg) {
    int e = blockIdx.x * blockDim.x + threadIdx.x;
    if (e >= NEDGES) return;
    atomicAdd(&deg[receivers[e]], 1);
}

__global__ void scan_kernel(const int* __restrict__ deg, int* __restrict__ rowstart) {
    __shared__ int lsum[256];
    __shared__ int loff[256];
    int t = threadIdx.x;
    int lo = t * 118;
    int hi = min(lo + 118, NNODES);
    int s = 0;
    for (int i = lo; i < hi; ++i) s += deg[i];
    lsum[t] = s;
    __syncthreads();
    if (t == 0) {
        int run = 0;
        for (int i = 0; i < 256; ++i) { loff[i] = run; run += lsum[i]; }
    }
    __syncthreads();
    int run = loff[t];
    for (int i = lo; i < hi; ++i) { rowstart[i] = run; run += deg[i]; }
    if (t == 0) rowstart[NNODES] = NEDGES;
}

__global__ void copy_cursor_kernel(const int* __restrict__ rowstart, int* __restrict__ cursor) {
    int i = blockIdx.x * blockDim.x + threadIdx.x;
    if (i < NNODES) cursor[i] = rowstart[i];
}

__global__ void fill_kernel(const int* __restrict__ receivers,
                            int* __restrict__ cursor, int* __restrict__ epos) {
    int e = blockIdx.x * blockDim.x + threadIdx.x;
    if (e >= NEDGES) return;
    epos[e] = atomicAdd(&cursor[receivers[e]], 1);
}

// ---------------------------------------------------------------- geometry, written directly in receiver-sorted order
__global__ void geom_perm_kernel(const float* __restrict__ vec,
                                 const int* __restrict__ senders,
                                 const int* __restrict__ epos,
                                 float* __restrict__ nh_perm,   // [E][4]
                                 int* __restrict__ snd_perm,    // [E]
                                 float* __restrict__ rb_perm) { // [E][8]
    int e = blockIdx.x * blockDim.x + threadIdx.x;
    if (e >= NEDGES) return;
    float vx = vec[3*e+0] * 0.25f;   // vectors / R_MAX
    float vy = vec[3*e+1] * 0.25f;
    float vz = vec[3*e+2] * 0.25f;
    float len = sqrtf(vx*vx + vy*vy + vz*vz);      // scaled length
    float inv = 1.f / fmaxf(len, 1e-9f);
    int p = epos[e];
    *(float4*)(nh_perm + (size_t)p*4) = make_float4(vx*inv, vy*inv, vz*inv, 0.f);
    snd_perm[p] = senders[e];
    float x = len * 0.25f;                         // lengths / R_MAX (again)
    float x3 = x*x*x;
    float x6 = x3*x3;
    float x7 = x6*x;
    float x8 = x7*x;
    float env = (x < 1.f) ? (1.f - 28.f*x6 + 48.f*x7 - 21.f*x8) : 0.f;
    float scale = 0.7071067811865476f * inv * env; // sqrt(2/R_MAX)/max(len,eps)*env
    float rbv[8];
    #pragma unroll
    for (int i = 0; i < NBASIS; ++i)
        rbv[i] = scale * sinf((float)(i+1) * 3.14159265358979f * x);
    *(float4*)(rb_perm + (size_t)p*8)     = make_float4(rbv[0], rbv[1], rbv[2], rbv[3]);
    *(float4*)(rb_perm + (size_t)p*8 + 4) = make_float4(rbv[4], rbv[5], rbv[6], rbv[7]);
}

// ---------------------------------------------------------------- weight prep (once)
__global__ void prepw_kernel(const float* __restrict__ w1, const float* __restrict__ w2,
                             const float* __restrict__ w3,
                             float* __restrict__ w1t, _Float16* __restrict__ w2f,
                             _Float16* __restrict__ w3f) {
    int t = blockIdx.x * blockDim.x + threadIdx.x;
    if (t < NL * 64 * 8) {
        int l = t / 512, r = t % 512, k = r >> 3, b = r & 7;
        w1t[t] = w1[l * 512 + b * 64 + k];
    }
    int u = t - NL * 64 * 8;
    if (u >= 0 && u < NL * 2 * 4 * 64 * 8) {
        int e = u & 7, lane = (u >> 3) & 63, nt = (u >> 9) & 3, ks = (u >> 11) & 1, l = u >> 12;
        int k = ks * 32 + ((lane >> 4) << 3) + e;
        int col = nt * 16 + (lane & 15);
        w2f[u] = (_Float16)w2[l * 4096 + k * 64 + col];
    }
    int v = t - NL * 64 * 8 - NL * 2 * 4 * 64 * 8;
    if (v >= 0 && v < NL * 2 * 10 * 64 * 8) {
        int q = v / 5120, rem = v % 5120;
        int l = q >> 1, ks = q & 1;
        int nt = rem >> 9, lane = (rem >> 3) & 63, e = rem & 7;
        int k = ks * 32 + ((lane >> 4) << 3) + e;
        int col = nt * 16 + (lane & 15);
        w3f[v] = (_Float16)w3[l * 10240 + k * 160 + col];
    }
}

// ---------------------------------------------------------------- node init (fp16 s)
__global__ void init_kernel(const int* __restrict__ specie,
                            const float* __restrict__ emb,
                            _Float16* __restrict__ s) {
    int t = blockIdx.x * blockDim.x + threadIdx.x;
    if (t >= NNODES * NC) return;
    int n = t >> 5;
    int c = t & 31;
    s[t] = (_Float16)emb[specie[n] * NC + c];
}

// ---------------------------------------------------------------- MFMA radial MLP
__global__ __launch_bounds__(256) void mlpm_kernel(
    const float* __restrict__ rb_perm,     // [E][8] permuted order
    const float* __restrict__ w1t,         // [64][8] f32
    const _Float16* __restrict__ w2f,      // [2][4][64][8]
    const _Float16* __restrict__ w3f,      // [2][10][64][8]
    _Float16* __restrict__ wgt16)          // gather-friendly layout
{
    __shared__ float w1lds[512];
    __shared__ __align__(16) _Float16 lds2[4][2688];  // per-wave: h2 tile (stride 72) then out tile [16][168]

    for (int t = threadIdx.x; t < 512; t += 256) w1lds[t] = w1t[t];
    __syncthreads();

    int lane = threadIdx.x & 63;
    int wid  = threadIdx.x >> 6;
    int c16 = lane & 15;
    int kg  = lane >> 4;
    int ibase = blockIdx.x * 64 + wid * 16;
    int g = blockIdx.x * 4 + wid;

    // ---- h1 (VALU): 16 values per lane, directly in A-frag layout
    float4 ra4 = *(const float4*)(rb_perm + (size_t)(ibase + c16) * 8);
    float4 rb4 = *(const float4*)(rb_perm + (size_t)(ibase + c16) * 8 + 4);

    half8v a0, a1;
    #pragma unroll
    for (int e = 0; e < 8; ++e) {
        const float* wr0 = w1lds + (kg * 8 + e) * 8;
        float d0;
        d0 = ra4.x * wr0[0];
        d0 = fmaf(ra4.y, wr0[1], d0);
        d0 = fmaf(ra4.z, wr0[2], d0);
        d0 = fmaf(ra4.w, wr0[3], d0);
        d0 = fmaf(rb4.x, wr0[4], d0);
        d0 = fmaf(rb4.y, wr0[5], d0);
        d0 = fmaf(rb4.z, wr0[6], d0);
        d0 = fmaf(rb4.w, wr0[7], d0);
        a0[e] = (_Float16)silu_f(d0);
        const float* wr1 = w1lds + (32 + kg * 8 + e) * 8;
        float d1;
        d1 = ra4.x * wr1[0];
        d1 = fmaf(ra4.y, wr1[1], d1);
        d1 = fmaf(ra4.z, wr1[2], d1);
        d1 = fmaf(ra4.w, wr1[3], d1);
        d1 = fmaf(rb4.x, wr1[4], d1);
        d1 = fmaf(rb4.y, wr1[5], d1);
        d1 = fmaf(rb4.z, wr1[6], d1);
        d1 = fmaf(rb4.w, wr1[7], d1);
        a1[e] = (_Float16)silu_f(d1);
    }

    // ---- h2 via W2 MFMA (M=16 edges, N=64, K=64); staged at stride 72
    _Float16* tw = &lds2[wid][0];
    float4v zero4 = {0.f, 0.f, 0.f, 0.f};
    #pragma unroll
    for (int nt = 0; nt < 4; ++nt) {
        half8v b0 = *(const half8v*)(w2f + (size_t)(nt) * 512 + lane * 8);
        half8v b1 = *(const half8v*)(w2f + (size_t)(4 + nt) * 512 + lane * 8);
        float4v acc = __builtin_amdgcn_mfma_f32_16x16x32_f16(a0, b0, zero4, 0, 0, 0);
        acc = __builtin_amdgcn_mfma_f32_16x16x32_f16(a1, b1, acc, 0, 0, 0);
        #pragma unroll
        for (int r = 0; r < 4; ++r)
            tw[(kg * 4 + r) * 72 + nt * 16 + c16] = (_Float16)silu_f(acc[r]);
    }

    // re-read h2 as A-frags (row = c16, k = ks*32 + kg*8 + e)
    half8v a2 = *(const half8v*)(tw + c16 * 72 + kg * 8);
    half8v a3 = *(const half8v*)(tw + c16 * 72 + 32 + kg * 8);

    // ---- wgt via W3 MFMA (N=160); stage into pair layout [16 edges][168]
    #pragma unroll
    for (int nt = 0; nt < 10; ++nt) {
        half8v b0 = *(const half8v*)(w3f + (size_t)(nt) * 512 + lane * 8);
        half8v b1 = *(const half8v*)(w3f + (size_t)(10 + nt) * 512 + lane * 8);
        float4v acc = __builtin_amdgcn_mfma_f32_16x16x32_f16(a2, b0, zero4, 0, 0, 0);
        acc = __builtin_amdgcn_mfma_f32_16x16x32_f16(a3, b1, acc, 0, 0, 0);
        int slot;
        if (nt < 4)      slot = nt * 32 + 2 * c16;             // h = nt*16+c16 < 64  -> 2h
        else if (nt < 8) slot = (nt - 4) * 32 + 2 * c16 + 1;   // 64..127 -> 2(h-64)+1
        else             slot = 128 + (nt - 8) * 16 + c16;     // 128..159 -> h
        #pragma unroll
        for (int r = 0; r < 4; ++r)
            tw[(kg * 4 + r) * 168 + slot] = (_Float16)acc[r];
    }

    // coalesced copy: 16 edges x 160 f16 (2560 f16 = 320 uint4) -> global
    _Float16* gout = wgt16 + (size_t)g * 2560;
    #pragma unroll
    for (int u = 0; u < 5; ++u) {
        int g4 = u * 64 + lane;        // 0..319
        int edge = g4 / 20;
        int part = g4 % 20;
        half8v vv = *(const half8v*)(tw + edge * 168 + part * 8);
        *(half8v*)(gout + edge * 160 + part * 8) = vv;
    }
}

// ---------------------------------------------------------------- gather + TP
// Wave per node; one-iteration-deep software pipeline: ALL of edge i+1's
// loads (snd/nh/wgt/features) issue during edge i's compute, so their
// latency is hidden by a full iteration.
__global__ __launch_bounds__(512) void gather_tp_kernel(
    const _Float16* __restrict__ wgt16,   // pair layout
    const float* __restrict__ nh_perm,    // [E][4]
    const int* __restrict__ snd_perm,     // [E]
    const int* __restrict__ rowstart, const int* __restrict__ deg,
    const _Float16* __restrict__ s_in, const _Float16* __restrict__ v_in,  // v: [N][3][32]
    float* __restrict__ agg_s,      // [N][64]
    float* __restrict__ agg_v)      // [N][96][3]
{
    int lane = threadIdx.x & 63;
    int wid  = threadIdx.x >> 6;
    int n = blockIdx.x * 8 + wid;
    if (n >= NNODES) return;

    int c = lane & 31;
    int half = lane >> 5;

    float accS = 0.f;
    float aVa0 = 0.f, aVa1 = 0.f, aVa2 = 0.f;   // half0: path2, half1: path3
    float aVb0 = 0.f, aVb1 = 0.f, aVb2 = 0.f;   // half0: path4, half1: garbage

    int start = rowstart[n];
    int cnt   = deg[n];

    // pipeline registers for edge i (loaded one iteration ahead)
    float4 nh_c = make_float4(0.f, 0.f, 0.f, 0.f);
    float d0_c = 0.f, d1_c = 0.f, d2_c = 0.f;
    float su_c = 0.f, v0_c = 0.f, v1_c = 0.f, v2_c = 0.f;
    if (cnt > 0) {
        int snd0 = snd_perm[start];
        nh_c = *(const float4*)(nh_perm + (size_t)start * 4);
        size_t gb = (size_t)(start >> 4) * 2560 + (size_t)(start & 15) * 160;
        half2v pr = u2h(*(const uint32*)(wgt16 + gb + lane * 2));
        d0_c = (float)pr.x;
        d1_c = (float)pr.y;
        d2_c = (float)wgt16[gb + 128 + c];
        su_c = (float)s_in[(size_t)snd0 * NC + c];
        v0_c = (float)v_in[(size_t)snd0 * 96 + c];
        v1_c = (float)v_in[(size_t)snd0 * 96 + 32 + c];
        v2_c = (float)v_in[(size_t)snd0 * 96 + 64 + c];
    }

    for (int i = 0; i < cnt; ++i) {
        // consume current
        float4 nh = nh_c;
        float d0 = d0_c, d1 = d1_c, d2f = d2_c;
        float su = su_c, v0 = v0_c, v1 = v1_c, v2 = v2_c;

        // issue ALL of edge i+1's loads now; results used next iteration
        if (i + 1 < cnt) {
            int idx1 = start + i + 1;
            int snd1 = snd_perm[idx1];
            nh_c = *(const float4*)(nh_perm + (size_t)idx1 * 4);
            size_t gb1 = (size_t)(idx1 >> 4) * 2560 + (size_t)(idx1 & 15) * 160;
            half2v pr1 = u2h(*(const uint32*)(wgt16 + gb1 + lane * 2));
            d0_c = (float)pr1.x;
            d1_c = (float)pr1.y;
            d2_c = (float)wgt16[gb1 + 128 + c];
            su_c = (float)s_in[(size_t)snd1 * NC + c];
            v0_c = (float)v_in[(size_t)snd1 * 96 + c];
            v1_c = (float)v_in[(size_t)snd1 * 96 + 32 + c];
            v2_c = (float)v_in[(size_t)snd1 * 96 + 64 + c];
        }

        // compute with current (independent of the loads above)
        float ndv = nh.x * v0;
        ndv = fmaf(nh.y, v1, ndv);
        ndv = fmaf(nh.z, v2, ndv);

        float sSel = half ? ndv : su;          // path1 vs path0 multiplier
        accS = fmaf(d0, sSel, accS);
        float scale = half ? d1 : d1 * su;     // path3: w3 ; path2: w2*su
        float f0 = half ? v0 : nh.x;
        float f1 = half ? v1 : nh.y;
        float f2 = half ? v2 : nh.z;
        aVa0 = fmaf(scale, f0, aVa0);
        aVa1 = fmaf(scale, f1, aVa1);
        aVa2 = fmaf(scale, f2, aVa2);
        float m4 = half ? 0.f : d2f;           // path4 only on half0
        aVb0 = fmaf(m4, fmaf(nh.x, ndv, -v0 * (1.f / 3.f)), aVb0);
        aVb1 = fmaf(m4, fmaf(nh.y, ndv, -v1 * (1.f / 3.f)), aVb1);
        aVb2 = fmaf(m4, fmaf(nh.z, ndv, -v2 * (1.f / 3.f)), aVb2);
    }

    agg_s[(size_t)n * 64 + lane] = accS;
    float* av = agg_v + (size_t)n * 288;
    if (half == 0) {
        av[c * 3 + 0] = aVa0; av[c * 3 + 1] = aVa1; av[c * 3 + 2] = aVa2;                      // path2
        av[(64 + c) * 3 + 0] = aVb0; av[(64 + c) * 3 + 1] = aVb1; av[(64 + c) * 3 + 2] = aVb2; // path4
    } else {
        av[(32 + c) * 3 + 0] = aVa0; av[(32 + c) * 3 + 1] = aVa1; av[(32 + c) * 3 + 2] = aVa2; // path3
    }
}

// ---------------------------------------------------------------- node update (fp16 features)
__global__ __launch_bounds__(256) void node_kernel(
    const int* __restrict__ specie,
    const float* __restrict__ agg_s, const float* __restrict__ agg_v,
    const _Float16* __restrict__ s_in,  const _Float16* __restrict__ v_in,
    const float* __restrict__ wls,   // [64][64]
    const float* __restrict__ wlv,   // [96][32]
    const float* __restrict__ wscs,  // [5][32][64]
    const float* __restrict__ wscv,  // [5][32][32]
    _Float16* __restrict__ s_out, _Float16* __restrict__ v_out)
{
    __shared__ float sAV[4][288];
    __shared__ float sVO[4][96];

    int lane = threadIdx.x & 63;
    int wid  = threadIdx.x >> 6;
    int n = blockIdx.x * 4 + wid;
    if (n >= NNODES) return;
    int sp = specie[n];

    const float* av = agg_v + (size_t)n * 288;
    sAV[wid][lane]       = av[lane];
    sAV[wid][64 + lane]  = av[64 + lane];
    sAV[wid][128 + lane] = av[128 + lane];
    sAV[wid][192 + lane] = av[192 + lane];
    if (lane < 32) sAV[wid][256 + lane] = av[256 + lane];
    const _Float16* vo = v_in + (size_t)n * 96;
    if (lane < 32) {
        sVO[wid][lane]      = (float)vo[lane];
        sVO[wid][32 + lane] = (float)vo[32 + lane];
        sVO[wid][64 + lane] = (float)vo[64 + lane];
    }

    float asv = agg_s[(size_t)n * 64 + lane];
    float sv  = (float)s_in[(size_t)n * 32 + (lane & 31)];

    __syncthreads();

    float sg = 0.f;
    #pragma unroll
    for (int j = 0; j < 64; ++j)
        sg = fmaf(rdlane(asv, j), wls[j * 64 + lane], sg);
    sg *= INV_AVG;
    const float* ws = wscs + (size_t)sp * 32 * 64;
    #pragma unroll
    for (int j = 0; j < 32; ++j)
        sg = fmaf(rdlane(sv, j), ws[j * 64 + lane], sg);
    float act  = silu_f(sg);
    float gate = __shfl(act, (lane & 31) + 32);

    int c = lane & 31;
    int h = lane >> 5;
    float vn1 = 0.f, vn2 = 0.f;
    #pragma unroll
    for (int p = 0; p < 96; ++p) {
        float w = wlv[p * 32 + c];
        vn1 = fmaf(sAV[wid][3 * p + h], w, vn1);
        vn2 = fmaf(sAV[wid][3 * p + 2], w, vn2);
    }
    vn1 *= INV_AVG; vn2 *= INV_AVG;
    const float* wv = wscv + (size_t)sp * 32 * 32;
    #pragma unroll
    for (int j = 0; j < 32; ++j) {
        float w = wv[j * 32 + c];
        vn1 = fmaf(sVO[wid][h * 32 + j], w, vn1);
        vn2 = fmaf(sVO[wid][64 + j],     w, vn2);
    }

    if (lane < 32) s_out[(size_t)n * 32 + lane] = (_Float16)act;
    v_out[(size_t)n * 96 + h * 32 + c] = (_Float16)(gate * vn1);
    if (h == 0) v_out[(size_t)n * 96 + 64 + c] = (_Float16)(gate * vn2);
}

// ---------------------------------------------------------------- output head
__global__ void out_kernel(const _Float16* __restrict__ s,
                           const float* __restrict__ w1,  // [32][16]
                           const float* __restrict__ w2,  // [16][1]
                           float* __restrict__ out) {
    int n = blockIdx.x * blockDim.x + threadIdx.x;
    if (n >= NNODES) return;
    float sv[NC];
    #pragma unroll
    for (int c = 0; c < NC; ++c) sv[c] = (float)s[(size_t)n * NC + c];
    float e = 0.f;
    #pragma unroll
    for (int j = 0; j < 16; ++j) {
        float tj = 0.f;
        #pragma unroll
        for (int c = 0; c < NC; ++c) tj += sv[c] * w1[c * 16 + j];
        e += tj * w2[j];
    }
    out[n] = e;
}

// ---------------------------------------------------------------- launcher
extern "C" void kernel_launch(void* const* d_in, const int* in_sizes, int n_in,
                              void* d_out, int out_size, void* d_ws, size_t ws_size,
                              hipStream_t stream) {
    const float* vectors   = (const float*)d_in[0];
    const int*   specie    = (const int*)  d_in[1];
    const int*   senders   = (const int*)  d_in[2];
    const int*   receivers = (const int*)  d_in[3];
    const float* emb       = (const float*)d_in[4];
    const float* w_rad1    = (const float*)d_in[5];
    const float* w_rad2    = (const float*)d_in[6];
    const float* w_rad_out = (const float*)d_in[7];
    const float* w_lin_s   = (const float*)d_in[8];
    const float* w_lin_v   = (const float*)d_in[9];
    const float* w_sc_s    = (const float*)d_in[10];
    const float* w_sc_v    = (const float*)d_in[11];
    const float* w_out1    = (const float*)d_in[12];
    const float* w_out2    = (const float*)d_in[13];

    char* base = (char*)d_ws;
    size_t off = 0;
    auto alloc = [&](size_t bytes) { char* q = base + off; off += (bytes + 255) & ~(size_t)255; return q; };

    float*    nh_perm  = (float*)alloc((size_t)NEDGES * 4 * 4);
    float*    rb_perm  = (float*)alloc((size_t)NEDGES * 8 * 4);
    int*      snd_perm = (int*)alloc((size_t)NEDGES * 4);
    int*      epos     = (int*)alloc((size_t)NEDGES * 4);
    _Float16* s_a      = (_Float16*)alloc((size_t)NNODES * NC * 2);
    _Float16* v_a      = (_Float16*)alloc((size_t)NNODES * NC * 3 * 2);
    _Float16* s_b      = (_Float16*)alloc((size_t)NNODES * NC * 2);
    _Float16* v_b      = (_Float16*)alloc((size_t)NNODES * NC * 3 * 2);
    float*    aggs     = (float*)alloc((size_t)NNODES * 2 * NC * 4);
    float*    aggv     = (float*)alloc((size_t)NNODES * 3 * NC * 3 * 4);
    int* deg        = (int*)alloc((size_t)NNODES * 4);
    int* rowstart   = (int*)alloc((size_t)(NNODES + 4) * 4);
    int* cursor     = (int*)alloc((size_t)NNODES * 4);
    float*    w1t      = (float*)alloc((size_t)NL * 64 * 8 * 4);
    _Float16* w2f      = (_Float16*)alloc((size_t)NL * 2 * 4 * 64 * 8 * 2);
    _Float16* w3f      = (_Float16*)alloc((size_t)NL * 2 * 10 * 64 * 8 * 2);
    _Float16* wgt16    = (_Float16*)alloc((size_t)NEDGES * 160 * 2);
    if (off > ws_size) return;   // workspace too small (should not happen; ~239 MB)

    // CSR + permuted geometry (once; graph static across layers)
    (void)hipMemsetAsync(deg, 0, NNODES * sizeof(int), stream);
    count_kernel<<<(NEDGES + 255) / 256, 256, 0, stream>>>(receivers, deg);
    scan_kernel<<<1, 256, 0, stream>>>(deg, rowstart);
    copy_cursor_kernel<<<(NNODES + 255) / 256, 256, 0, stream>>>(rowstart, cursor);
    fill_kernel<<<(NEDGES + 255) / 256, 256, 0, stream>>>(receivers, cursor, epos);
    geom_perm_kernel<<<(NEDGES + 255) / 256, 256, 0, stream>>>(
        vectors, senders, epos, nh_perm, snd_perm, rb_perm);
    int prep_n = NL * 64 * 8 + NL * 2 * 4 * 64 * 8 + NL * 2 * 10 * 64 * 8;
    prepw_kernel<<<(prep_n + 255) / 256, 256, 0, stream>>>(
        w_rad1, w_rad2, w_rad_out, w1t, w2f, w3f);

    init_kernel<<<(NNODES * NC + 255) / 256, 256, 0, stream>>>(specie, emb, s_a);
    (void)hipMemsetAsync(v_a, 0, (size_t)NNODES * NC * 3 * 2, stream);

    _Float16* si = s_a; _Float16* vi = v_a; _Float16* so = s_b; _Float16* vo = v_b;
    for (int l = 0; l < NL; ++l) {
        mlpm_kernel<<<NEDGES / 64, 256, 0, stream>>>(
            rb_perm,
            w1t + (size_t)l * 512,
            w2f + (size_t)l * 4096,
            w3f + (size_t)l * 10240,
            wgt16);
        gather_tp_kernel<<<(NNODES + 7) / 8, 512, 0, stream>>>(
            wgt16, nh_perm, snd_perm, rowstart, deg, si, vi, aggs, aggv);
        node_kernel<<<(NNODES + 3) / 4, 256, 0, stream>>>(
            specie, aggs, aggv, si, vi,
            w_lin_s + (size_t)l * 64 * 64,
            w_lin_v + (size_t)l * 96 * 32,
            w_sc_s + (size_t)l * NSPEC * NC * 64,
            w_sc_v + (size_t)l * NSPEC * NC * NC,
            so, vo);
        _Float16* ts = si; si = so; so = ts;
        _Float16* tv = vi; vi = vo; vo = tv;
    }

    out_kernel<<<(NNODES + 255) / 256, 256, 0, stream>>>(si, w_out1, w_out2, (float*)d_out);
}

// Round 19
// 693.591 us; speedup vs baseline: 1.0387x; 1.0387x over previous
//
#include <hip/hip_runtime.h>
#include <math.h>

#define NNODES 30000
#define NEDGES 480000
#define NC 32
#define NL 3
#define NH 64
#define NBASIS 8
#define NSPEC 5
#define INV_AVG 0.0625f   // 1 / AVG_NEIGH

typedef _Float16 half2v __attribute__((ext_vector_type(2)));
typedef _Float16 half4v __attribute__((ext_vector_type(4)));
typedef _Float16 half8v __attribute__((ext_vector_type(8)));
typedef float    float4v __attribute__((ext_vector_type(4)));
typedef unsigned int uint32;

__device__ __forceinline__ float silu_f(float x) {
    return x / (1.f + __expf(-x));
}
__device__ __forceinline__ float rdlane(float v, int k) {
    return __uint_as_float(__builtin_amdgcn_readlane(__float_as_uint(v), k));
}
__device__ __forceinline__ half2v u2h(uint32 u) {
    union { uint32 u; half2v h; } x; x.u = u; return x.h;
}

// wgt16 layout (gather-friendly, per 16-edge group g = gi>>4, el = gi&15):
//   f16 index = g*2560 + el*160 + pos(h)
//   pos(h) = 2h (h<64) | 2(h-64)+1 (64<=h<128) | h (h>=128)

// ---------------------------------------------------------------- CSR build (merged count+fill)
__global__ void fill_kernel(const int* __restrict__ receivers,
                            int* __restrict__ deg, int* __restrict__ epos) {
    int e = blockIdx.x * blockDim.x + threadIdx.x;
    if (e >= NEDGES) return;
    epos[e] = atomicAdd(&deg[receivers[e]], 1);   // local offset within receiver row
}

__global__ void scan_kernel(const int* __restrict__ deg, int* __restrict__ rowstart) {
    __shared__ int lsum[256];
    __shared__ int loff[256];
    int t = threadIdx.x;
    int lo = t * 118;
    int hi = min(lo + 118, NNODES);
    int s = 0;
    for (int i = lo; i < hi; ++i) s += deg[i];
    lsum[t] = s;
    __syncthreads();
    if (t == 0) {
        int run = 0;
        for (int i = 0; i < 256; ++i) { loff[i] = run; run += lsum[i]; }
    }
    __syncthreads();
    int run = loff[t];
    for (int i = lo; i < hi; ++i) { rowstart[i] = run; run += deg[i]; }
    if (t == 0) rowstart[NNODES] = NEDGES;
}

// ---------------------------------------------------------------- geometry, written directly in receiver-sorted order
__global__ void geom_perm_kernel(const float* __restrict__ vec,
                                 const int* __restrict__ senders,
                                 const int* __restrict__ receivers,
                                 const int* __restrict__ rowstart,
                                 const int* __restrict__ epos,
                                 float* __restrict__ nh_perm,   // [E][4]
                                 int* __restrict__ snd_perm,    // [E]
                                 float* __restrict__ rb_perm) { // [E][8]
    int e = blockIdx.x * blockDim.x + threadIdx.x;
    if (e >= NEDGES) return;
    float vx = vec[3*e+0] * 0.25f;   // vectors / R_MAX
    float vy = vec[3*e+1] * 0.25f;
    float vz = vec[3*e+2] * 0.25f;
    float len = sqrtf(vx*vx + vy*vy + vz*vz);      // scaled length
    float inv = 1.f / fmaxf(len, 1e-9f);
    int p = rowstart[receivers[e]] + epos[e];
    *(float4*)(nh_perm + (size_t)p*4) = make_float4(vx*inv, vy*inv, vz*inv, 0.f);
    snd_perm[p] = senders[e];
    float x = len * 0.25f;                         // lengths / R_MAX (again)
    float x3 = x*x*x;
    float x6 = x3*x3;
    float x7 = x6*x;
    float x8 = x7*x;
    float env = (x < 1.f) ? (1.f - 28.f*x6 + 48.f*x7 - 21.f*x8) : 0.f;
    float scale = 0.7071067811865476f * inv * env; // sqrt(2/R_MAX)/max(len,eps)*env
    float rbv[8];
    #pragma unroll
    for (int i = 0; i < NBASIS; ++i)
        rbv[i] = scale * sinf((float)(i+1) * 3.14159265358979f * x);
    *(float4*)(rb_perm + (size_t)p*8)     = make_float4(rbv[0], rbv[1], rbv[2], rbv[3]);
    *(float4*)(rb_perm + (size_t)p*8 + 4) = make_float4(rbv[4], rbv[5], rbv[6], rbv[7]);
}

// ---------------------------------------------------------------- weight prep (once)
__global__ void prepw_kernel(const float* __restrict__ w1, const float* __restrict__ w2,
                             const float* __restrict__ w3,
                             float* __restrict__ w1t, _Float16* __restrict__ w2f,
                             _Float16* __restrict__ w3f) {
    int t = blockIdx.x * blockDim.x + threadIdx.x;
    if (t < NL * 64 * 8) {
        int l = t / 512, r = t % 512, k = r >> 3, b = r & 7;
        w1t[t] = w1[l * 512 + b * 64 + k];
    }
    int u = t - NL * 64 * 8;
    if (u >= 0 && u < NL * 2 * 4 * 64 * 8) {
        int e = u & 7, lane = (u >> 3) & 63, nt = (u >> 9) & 3, ks = (u >> 11) & 1, l = u >> 12;
        int k = ks * 32 + ((lane >> 4) << 3) + e;
        int col = nt * 16 + (lane & 15);
        w2f[u] = (_Float16)w2[l * 4096 + k * 64 + col];
    }
    int v = t - NL * 64 * 8 - NL * 2 * 4 * 64 * 8;
    if (v >= 0 && v < NL * 2 * 10 * 64 * 8) {
        int q = v / 5120, rem = v % 5120;
        int l = q >> 1, ks = q & 1;
        int nt = rem >> 9, lane = (rem >> 3) & 63, e = rem & 7;
        int k = ks * 32 + ((lane >> 4) << 3) + e;
        int col = nt * 16 + (lane & 15);
        w3f[v] = (_Float16)w3[l * 10240 + k * 160 + col];
    }
}

// ---------------------------------------------------------------- node init (fp16 s)
__global__ void init_kernel(const int* __restrict__ specie,
                            const float* __restrict__ emb,
                            _Float16* __restrict__ s) {
    int t = blockIdx.x * blockDim.x + threadIdx.x;
    if (t >= NNODES * NC) return;
    int n = t >> 5;
    int c = t & 31;
    s[t] = (_Float16)emb[specie[n] * NC + c];
}

// ---------------------------------------------------------------- MFMA radial MLP
__global__ __launch_bounds__(256) void mlpm_kernel(
    const float* __restrict__ rb_perm,     // [E][8] permuted order
    const float* __restrict__ w1t,         // [64][8] f32
    const _Float16* __restrict__ w2f,      // [2][4][64][8]
    const _Float16* __restrict__ w3f,      // [2][10][64][8]
    _Float16* __restrict__ wgt16)          // gather-friendly layout
{
    __shared__ float w1lds[512];
    __shared__ __align__(16) _Float16 lds2[4][2688];  // per-wave: h2 tile (stride 72) then out tile [16][168]

    for (int t = threadIdx.x; t < 512; t += 256) w1lds[t] = w1t[t];
    __syncthreads();

    int lane = threadIdx.x & 63;
    int wid  = threadIdx.x >> 6;
    int c16 = lane & 15;
    int kg  = lane >> 4;
    int ibase = blockIdx.x * 64 + wid * 16;
    int g = blockIdx.x * 4 + wid;

    // ---- h1 (VALU): 16 values per lane, directly in A-frag layout
    float4 ra4 = *(const float4*)(rb_perm + (size_t)(ibase + c16) * 8);
    float4 rb4 = *(const float4*)(rb_perm + (size_t)(ibase + c16) * 8 + 4);

    half8v a0, a1;
    #pragma unroll
    for (int e = 0; e < 8; ++e) {
        const float* wr0 = w1lds + (kg * 8 + e) * 8;
        float d0;
        d0 = ra4.x * wr0[0];
        d0 = fmaf(ra4.y, wr0[1], d0);
        d0 = fmaf(ra4.z, wr0[2], d0);
        d0 = fmaf(ra4.w, wr0[3], d0);
        d0 = fmaf(rb4.x, wr0[4], d0);
        d0 = fmaf(rb4.y, wr0[5], d0);
        d0 = fmaf(rb4.z, wr0[6], d0);
        d0 = fmaf(rb4.w, wr0[7], d0);
        a0[e] = (_Float16)silu_f(d0);
        const float* wr1 = w1lds + (32 + kg * 8 + e) * 8;
        float d1;
        d1 = ra4.x * wr1[0];
        d1 = fmaf(ra4.y, wr1[1], d1);
        d1 = fmaf(ra4.z, wr1[2], d1);
        d1 = fmaf(ra4.w, wr1[3], d1);
        d1 = fmaf(rb4.x, wr1[4], d1);
        d1 = fmaf(rb4.y, wr1[5], d1);
        d1 = fmaf(rb4.z, wr1[6], d1);
        d1 = fmaf(rb4.w, wr1[7], d1);
        a1[e] = (_Float16)silu_f(d1);
    }

    // ---- h2 via W2 MFMA (M=16 edges, N=64, K=64); staged at stride 72
    _Float16* tw = &lds2[wid][0];
    float4v zero4 = {0.f, 0.f, 0.f, 0.f};
    #pragma unroll
    for (int nt = 0; nt < 4; ++nt) {
        half8v b0 = *(const half8v*)(w2f + (size_t)(nt) * 512 + lane * 8);
        half8v b1 = *(const half8v*)(w2f + (size_t)(4 + nt) * 512 + lane * 8);
        float4v acc = __builtin_amdgcn_mfma_f32_16x16x32_f16(a0, b0, zero4, 0, 0, 0);
        acc = __builtin_amdgcn_mfma_f32_16x16x32_f16(a1, b1, acc, 0, 0, 0);
        #pragma unroll
        for (int r = 0; r < 4; ++r)
            tw[(kg * 4 + r) * 72 + nt * 16 + c16] = (_Float16)silu_f(acc[r]);
    }

    // re-read h2 as A-frags (row = c16, k = ks*32 + kg*8 + e)
    half8v a2 = *(const half8v*)(tw + c16 * 72 + kg * 8);
    half8v a3 = *(const half8v*)(tw + c16 * 72 + 32 + kg * 8);

    // ---- wgt via W3 MFMA (N=160); stage into pair layout [16 edges][168]
    #pragma unroll
    for (int nt = 0; nt < 10; ++nt) {
        half8v b0 = *(const half8v*)(w3f + (size_t)(nt) * 512 + lane * 8);
        half8v b1 = *(const half8v*)(w3f + (size_t)(10 + nt) * 512 + lane * 8);
        float4v acc = __builtin_amdgcn_mfma_f32_16x16x32_f16(a2, b0, zero4, 0, 0, 0);
        acc = __builtin_amdgcn_mfma_f32_16x16x32_f16(a3, b1, acc, 0, 0, 0);
        int slot;
        if (nt < 4)      slot = nt * 32 + 2 * c16;             // h = nt*16+c16 < 64  -> 2h
        else if (nt < 8) slot = (nt - 4) * 32 + 2 * c16 + 1;   // 64..127 -> 2(h-64)+1
        else             slot = 128 + (nt - 8) * 16 + c16;     // 128..159 -> h
        #pragma unroll
        for (int r = 0; r < 4; ++r)
            tw[(kg * 4 + r) * 168 + slot] = (_Float16)acc[r];
    }

    // coalesced copy: 16 edges x 160 f16 (2560 f16 = 320 uint4) -> global
    _Float16* gout = wgt16 + (size_t)g * 2560;
    #pragma unroll
    for (int u = 0; u < 5; ++u) {
        int g4 = u * 64 + lane;        // 0..319
        int edge = g4 / 20;
        int part = g4 % 20;
        half8v vv = *(const half8v*)(tw + edge * 168 + part * 8);
        *(half8v*)(gout + edge * 160 + part * 8) = vv;
    }
}

// ---------------------------------------------------------------- gather + TP (fp16 agg out)
__global__ __launch_bounds__(512) void gather_tp_kernel(
    const _Float16* __restrict__ wgt16,   // pair layout
    const float* __restrict__ nh_perm,    // [E][4]
    const int* __restrict__ snd_perm,     // [E]
    const int* __restrict__ rowstart, const int* __restrict__ deg,
    const _Float16* __restrict__ s_in, const _Float16* __restrict__ v_in,  // v: [N][3][32]
    _Float16* __restrict__ agg_s,   // [N][64]
    _Float16* __restrict__ agg_v)   // [N][96][3]
{
    int lane = threadIdx.x & 63;
    int wid  = threadIdx.x >> 6;
    int n = blockIdx.x * 8 + wid;
    if (n >= NNODES) return;

    int c = lane & 31;
    int half = lane >> 5;

    float accS = 0.f;
    float aVa0 = 0.f, aVa1 = 0.f, aVa2 = 0.f;   // half0: path2, half1: path3
    float aVb0 = 0.f, aVb1 = 0.f, aVb2 = 0.f;   // half0: path4, half1: garbage

    int start = rowstart[n];
    int cnt   = deg[n];

    // pipeline registers for edge i (loaded one iteration ahead)
    float4 nh_c = make_float4(0.f, 0.f, 0.f, 0.f);
    float d0_c = 0.f, d1_c = 0.f, d2_c = 0.f;
    float su_c = 0.f, v0_c = 0.f, v1_c = 0.f, v2_c = 0.f;
    if (cnt > 0) {
        int snd0 = snd_perm[start];
        nh_c = *(const float4*)(nh_perm + (size_t)start * 4);
        size_t gb = (size_t)(start >> 4) * 2560 + (size_t)(start & 15) * 160;
        half2v pr = u2h(*(const uint32*)(wgt16 + gb + lane * 2));
        d0_c = (float)pr.x;
        d1_c = (float)pr.y;
        d2_c = (float)wgt16[gb + 128 + c];
        su_c = (float)s_in[(size_t)snd0 * NC + c];
        v0_c = (float)v_in[(size_t)snd0 * 96 + c];
        v1_c = (float)v_in[(size_t)snd0 * 96 + 32 + c];
        v2_c = (float)v_in[(size_t)snd0 * 96 + 64 + c];
    }

    for (int i = 0; i < cnt; ++i) {
        float4 nh = nh_c;
        float d0 = d0_c, d1 = d1_c, d2f = d2_c;
        float su = su_c, v0 = v0_c, v1 = v1_c, v2 = v2_c;

        if (i + 1 < cnt) {
            int idx1 = start + i + 1;
            int snd1 = snd_perm[idx1];
            nh_c = *(const float4*)(nh_perm + (size_t)idx1 * 4);
            size_t gb1 = (size_t)(idx1 >> 4) * 2560 + (size_t)(idx1 & 15) * 160;
            half2v pr1 = u2h(*(const uint32*)(wgt16 + gb1 + lane * 2));
            d0_c = (float)pr1.x;
            d1_c = (float)pr1.y;
            d2_c = (float)wgt16[gb1 + 128 + c];
            su_c = (float)s_in[(size_t)snd1 * NC + c];
            v0_c = (float)v_in[(size_t)snd1 * 96 + c];
            v1_c = (float)v_in[(size_t)snd1 * 96 + 32 + c];
            v2_c = (float)v_in[(size_t)snd1 * 96 + 64 + c];
        }

        float ndv = nh.x * v0;
        ndv = fmaf(nh.y, v1, ndv);
        ndv = fmaf(nh.z, v2, ndv);

        float sSel = half ? ndv : su;          // path1 vs path0 multiplier
        accS = fmaf(d0, sSel, accS);
        float scale = half ? d1 : d1 * su;     // path3: w3 ; path2: w2*su
        float f0 = half ? v0 : nh.x;
        float f1 = half ? v1 : nh.y;
        float f2 = half ? v2 : nh.z;
        aVa0 = fmaf(scale, f0, aVa0);
        aVa1 = fmaf(scale, f1, aVa1);
        aVa2 = fmaf(scale, f2, aVa2);
        float m4 = half ? 0.f : d2f;           // path4 only on half0
        aVb0 = fmaf(m4, fmaf(nh.x, ndv, -v0 * (1.f / 3.f)), aVb0);
        aVb1 = fmaf(m4, fmaf(nh.y, ndv, -v1 * (1.f / 3.f)), aVb1);
        aVb2 = fmaf(m4, fmaf(nh.z, ndv, -v2 * (1.f / 3.f)), aVb2);
    }

    agg_s[(size_t)n * 64 + lane] = (_Float16)accS;
    _Float16* av = agg_v + (size_t)n * 288;
    if (half == 0) {
        av[c * 3 + 0] = (_Float16)aVa0; av[c * 3 + 1] = (_Float16)aVa1; av[c * 3 + 2] = (_Float16)aVa2;                      // path2
        av[(64 + c) * 3 + 0] = (_Float16)aVb0; av[(64 + c) * 3 + 1] = (_Float16)aVb1; av[(64 + c) * 3 + 2] = (_Float16)aVb2; // path4
    } else {
        av[(32 + c) * 3 + 0] = (_Float16)aVa0; av[(32 + c) * 3 + 1] = (_Float16)aVa1; av[(32 + c) * 3 + 2] = (_Float16)aVa2; // path3
    }
}

// ---------------------------------------------------------------- node update (fp16 agg in)
__global__ __launch_bounds__(256) void node_kernel(
    const int* __restrict__ specie,
    const _Float16* __restrict__ agg_s, const _Float16* __restrict__ agg_v,
    const _Float16* __restrict__ s_in,  const _Float16* __restrict__ v_in,
    const float* __restrict__ wls,   // [64][64]
    const float* __restrict__ wlv,   // [96][32]
    const float* __restrict__ wscs,  // [5][32][64]
    const float* __restrict__ wscv,  // [5][32][32]
    _Float16* __restrict__ s_out, _Float16* __restrict__ v_out)
{
    __shared__ float sAV[4][288];
    __shared__ float sVO[4][96];

    int lane = threadIdx.x & 63;
    int wid  = threadIdx.x >> 6;
    int n = blockIdx.x * 4 + wid;
    if (n >= NNODES) return;
    int sp = specie[n];

    const _Float16* av = agg_v + (size_t)n * 288;
    sAV[wid][lane]       = (float)av[lane];
    sAV[wid][64 + lane]  = (float)av[64 + lane];
    sAV[wid][128 + lane] = (float)av[128 + lane];
    sAV[wid][192 + lane] = (float)av[192 + lane];
    if (lane < 32) sAV[wid][256 + lane] = (float)av[256 + lane];
    const _Float16* vo = v_in + (size_t)n * 96;
    if (lane < 32) {
        sVO[wid][lane]      = (float)vo[lane];
        sVO[wid][32 + lane] = (float)vo[32 + lane];
        sVO[wid][64 + lane] = (float)vo[64 + lane];
    }

    float asv = (float)agg_s[(size_t)n * 64 + lane];
    float sv  = (float)s_in[(size_t)n * 32 + (lane & 31)];

    __syncthreads();

    float sg = 0.f;
    #pragma unroll
    for (int j = 0; j < 64; ++j)
        sg = fmaf(rdlane(asv, j), wls[j * 64 + lane], sg);
    sg *= INV_AVG;
    const float* ws = wscs + (size_t)sp * 32 * 64;
    #pragma unroll
    for (int j = 0; j < 32; ++j)
        sg = fmaf(rdlane(sv, j), ws[j * 64 + lane], sg);
    float act  = silu_f(sg);
    float gate = __shfl(act, (lane & 31) + 32);

    int c = lane & 31;
    int h = lane >> 5;
    float vn1 = 0.f, vn2 = 0.f;
    #pragma unroll
    for (int p = 0; p < 96; ++p) {
        float w = wlv[p * 32 + c];
        vn1 = fmaf(sAV[wid][3 * p + h], w, vn1);
        vn2 = fmaf(sAV[wid][3 * p + 2], w, vn2);
    }
    vn1 *= INV_AVG; vn2 *= INV_AVG;
    const float* wv = wscv + (size_t)sp * 32 * 32;
    #pragma unroll
    for (int j = 0; j < 32; ++j) {
        float w = wv[j * 32 + c];
        vn1 = fmaf(sVO[wid][h * 32 + j], w, vn1);
        vn2 = fmaf(sVO[wid][64 + j],     w, vn2);
    }

    if (lane < 32) s_out[(size_t)n * 32 + lane] = (_Float16)act;
    v_out[(size_t)n * 96 + h * 32 + c] = (_Float16)(gate * vn1);
    if (h == 0) v_out[(size_t)n * 96 + 64 + c] = (_Float16)(gate * vn2);
}

// ---------------------------------------------------------------- output head
__global__ void out_kernel(const _Float16* __restrict__ s,
                           const float* __restrict__ w1,  // [32][16]
                           const float* __restrict__ w2,  // [16][1]
                           float* __restrict__ out) {
    int n = blockIdx.x * blockDim.x + threadIdx.x;
    if (n >= NNODES) return;
    float sv[NC];
    #pragma unroll
    for (int c = 0; c < NC; ++c) sv[c] = (float)s[(size_t)n * NC + c];
    float e = 0.f;
    #pragma unroll
    for (int j = 0; j < 16; ++j) {
        float tj = 0.f;
        #pragma unroll
        for (int c = 0; c < NC; ++c) tj += sv[c] * w1[c * 16 + j];
        e += tj * w2[j];
    }
    out[n] = e;
}

// ---------------------------------------------------------------- launcher
extern "C" void kernel_launch(void* const* d_in, const int* in_sizes, int n_in,
                              void* d_out, int out_size, void* d_ws, size_t ws_size,
                              hipStream_t stream) {
    const float* vectors   = (const float*)d_in[0];
    const int*   specie    = (const int*)  d_in[1];
    const int*   senders   = (const int*)  d_in[2];
    const int*   receivers = (const int*)  d_in[3];
    const float* emb       = (const float*)d_in[4];
    const float* w_rad1    = (const float*)d_in[5];
    const float* w_rad2    = (const float*)d_in[6];
    const float* w_rad_out = (const float*)d_in[7];
    const float* w_lin_s   = (const float*)d_in[8];
    const float* w_lin_v   = (const float*)d_in[9];
    const float* w_sc_s    = (const float*)d_in[10];
    const float* w_sc_v    = (const float*)d_in[11];
    const float* w_out1    = (const float*)d_in[12];
    const float* w_out2    = (const float*)d_in[13];

    char* base = (char*)d_ws;
    size_t off = 0;
    auto alloc = [&](size_t bytes) { char* q = base + off; off += (bytes + 255) & ~(size_t)255; return q; };

    float*    nh_perm  = (float*)alloc((size_t)NEDGES * 4 * 4);
    float*    rb_perm  = (float*)alloc((size_t)NEDGES * 8 * 4);
    int*      snd_perm = (int*)alloc((size_t)NEDGES * 4);
    int*      epos     = (int*)alloc((size_t)NEDGES * 4);
    _Float16* s_a      = (_Float16*)alloc((size_t)NNODES * NC * 2);
    _Float16* v_a      = (_Float16*)alloc((size_t)NNODES * NC * 3 * 2);
    _Float16* s_b      = (_Float16*)alloc((size_t)NNODES * NC * 2);
    _Float16* v_b      = (_Float16*)alloc((size_t)NNODES * NC * 3 * 2);
    _Float16* aggs     = (_Float16*)alloc((size_t)NNODES * 2 * NC * 2);
    _Float16* aggv     = (_Float16*)alloc((size_t)NNODES * 3 * NC * 3 * 2);
    int* deg        = (int*)alloc((size_t)NNODES * 4);
    int* rowstart   = (int*)alloc((size_t)(NNODES + 4) * 4);
    float*    w1t      = (float*)alloc((size_t)NL * 64 * 8 * 4);
    _Float16* w2f      = (_Float16*)alloc((size_t)NL * 2 * 4 * 64 * 8 * 2);
    _Float16* w3f      = (_Float16*)alloc((size_t)NL * 2 * 10 * 64 * 8 * 2);
    _Float16* wgt16    = (_Float16*)alloc((size_t)NEDGES * 160 * 2);
    if (off > ws_size) return;   // workspace too small (should not happen; ~220 MB)

    // CSR + permuted geometry (once; graph static across layers)
    (void)hipMemsetAsync(deg, 0, NNODES * sizeof(int), stream);
    fill_kernel<<<(NEDGES + 255) / 256, 256, 0, stream>>>(receivers, deg, epos);
    scan_kernel<<<1, 256, 0, stream>>>(deg, rowstart);
    geom_perm_kernel<<<(NEDGES + 255) / 256, 256, 0, stream>>>(
        vectors, senders, receivers, rowstart, epos, nh_perm, snd_perm, rb_perm);
    int prep_n = NL * 64 * 8 + NL * 2 * 4 * 64 * 8 + NL * 2 * 10 * 64 * 8;
    prepw_kernel<<<(prep_n + 255) / 256, 256, 0, stream>>>(
        w_rad1, w_rad2, w_rad_out, w1t, w2f, w3f);

    init_kernel<<<(NNODES * NC + 255) / 256, 256, 0, stream>>>(specie, emb, s_a);
    (void)hipMemsetAsync(v_a, 0, (size_t)NNODES * NC * 3 * 2, stream);

    _Float16* si = s_a; _Float16* vi = v_a; _Float16* so = s_b; _Float16* vo = v_b;
    for (int l = 0; l < NL; ++l) {
        mlpm_kernel<<<NEDGES / 64, 256, 0, stream>>>(
            rb_perm,
            w1t + (size_t)l * 512,
            w2f + (size_t)l * 4096,
            w3f + (size_t)l * 10240,
            wgt16);
        gather_tp_kernel<<<(NNODES + 7) / 8, 512, 0, stream>>>(
            wgt16, nh_perm, snd_perm, rowstart, deg, si, vi, aggs, aggv);
        node_kernel<<<(NNODES + 3) / 4, 256, 0, stream>>>(
            specie, aggs, aggv, si, vi,
            w_lin_s + (size_t)l * 64 * 64,
            w_lin_v + (size_t)l * 96 * 32,
            w_sc_s + (size_t)l * NSPEC * NC * 64,
            w_sc_v + (size_t)l * NSPEC * NC * NC,
            so, vo);
        _Float16* ts = si; si = so; so = ts;
        _Float16* tv = vi; vi = vo; vo = tv;
    }

    out_kernel<<<(NNODES + 255) / 256, 256, 0, stream>>>(si, w_out1, w_out2, (float*)d_out);
}

// Round 20
// 687.086 us; speedup vs baseline: 1.0485x; 1.0095x over previous
//
#include <hip/hip_runtime.h>
#include <math.h>

#define NNODES 30000
#define NEDGES 480000
#define NC 32
#define NL 3
#define NH 64
#define NBASIS 8
#define NSPEC 5
#define INV_AVG 0.0625f   // 1 / AVG_NEIGH

typedef _Float16 half2v __attribute__((ext_vector_type(2)));
typedef _Float16 half4v __attribute__((ext_vector_type(4)));
typedef _Float16 half8v __attribute__((ext_vector_type(8)));
typedef float    float4v __attribute__((ext_vector_type(4)));
typedef unsigned int uint32;

__device__ __forceinline__ float silu_f(float x) {
    return x / (1.f + __expf(-x));
}
__device__ __forceinline__ float rdlane(float v, int k) {
    return __uint_as_float(__builtin_amdgcn_readlane(__float_as_uint(v), k));
}
__device__ __forceinline__ half2v u2h(uint32 u) {
    union { uint32 u; half2v h; } x; x.u = u; return x.h;
}

// sv4 layout: [N][32][4] f16 = (v_x, v_y, v_z, s) per (node, channel) -> one 8B record
// wgt16 layout (gather-friendly, per 16-edge group g = gi>>4, el = gi&15):
//   f16 index = g*2560 + el*160 + pos(h);  pos(h) = 2h | 2(h-64)+1 | h

// ---------------------------------------------------------------- CSR build (merged count+fill)
__global__ void fill_kernel(const int* __restrict__ receivers,
                            int* __restrict__ deg, int* __restrict__ epos) {
    int e = blockIdx.x * blockDim.x + threadIdx.x;
    if (e >= NEDGES) return;
    epos[e] = atomicAdd(&deg[receivers[e]], 1);   // local offset within receiver row
}

__global__ void scan_kernel(const int* __restrict__ deg, int* __restrict__ rowstart) {
    __shared__ int lsum[256];
    __shared__ int loff[256];
    int t = threadIdx.x;
    int lo = t * 118;
    int hi = min(lo + 118, NNODES);
    int s = 0;
    for (int i = lo; i < hi; ++i) s += deg[i];
    lsum[t] = s;
    __syncthreads();
    if (t == 0) {
        int run = 0;
        for (int i = 0; i < 256; ++i) { loff[i] = run; run += lsum[i]; }
    }
    __syncthreads();
    int run = loff[t];
    for (int i = lo; i < hi; ++i) { rowstart[i] = run; run += deg[i]; }
    if (t == 0) rowstart[NNODES] = NEDGES;
}

// ---------------------------------------------------------------- geometry, written directly in receiver-sorted order
__global__ void geom_perm_kernel(const float* __restrict__ vec,
                                 const int* __restrict__ senders,
                                 const int* __restrict__ receivers,
                                 const int* __restrict__ rowstart,
                                 const int* __restrict__ epos,
                                 float* __restrict__ nh_perm,   // [E][4]
                                 int* __restrict__ snd_perm,    // [E]
                                 float* __restrict__ rb_perm) { // [E][8]
    int e = blockIdx.x * blockDim.x + threadIdx.x;
    if (e >= NEDGES) return;
    float vx = vec[3*e+0] * 0.25f;   // vectors / R_MAX
    float vy = vec[3*e+1] * 0.25f;
    float vz = vec[3*e+2] * 0.25f;
    float len = sqrtf(vx*vx + vy*vy + vz*vz);      // scaled length
    float inv = 1.f / fmaxf(len, 1e-9f);
    int p = rowstart[receivers[e]] + epos[e];
    *(float4*)(nh_perm + (size_t)p*4) = make_float4(vx*inv, vy*inv, vz*inv, 0.f);
    snd_perm[p] = senders[e];
    float x = len * 0.25f;                         // lengths / R_MAX (again)
    float x3 = x*x*x;
    float x6 = x3*x3;
    float x7 = x6*x;
    float x8 = x7*x;
    float env = (x < 1.f) ? (1.f - 28.f*x6 + 48.f*x7 - 21.f*x8) : 0.f;
    float scale = 0.7071067811865476f * inv * env; // sqrt(2/R_MAX)/max(len,eps)*env
    float rbv[8];
    #pragma unroll
    for (int i = 0; i < NBASIS; ++i)
        rbv[i] = scale * sinf((float)(i+1) * 3.14159265358979f * x);
    *(float4*)(rb_perm + (size_t)p*8)     = make_float4(rbv[0], rbv[1], rbv[2], rbv[3]);
    *(float4*)(rb_perm + (size_t)p*8 + 4) = make_float4(rbv[4], rbv[5], rbv[6], rbv[7]);
}

// ---------------------------------------------------------------- weight prep (once)
__global__ void prepw_kernel(const float* __restrict__ w1, const float* __restrict__ w2,
                             const float* __restrict__ w3,
                             float* __restrict__ w1t, _Float16* __restrict__ w2f,
                             _Float16* __restrict__ w3f) {
    int t = blockIdx.x * blockDim.x + threadIdx.x;
    if (t < NL * 64 * 8) {
        int l = t / 512, r = t % 512, k = r >> 3, b = r & 7;
        w1t[t] = w1[l * 512 + b * 64 + k];
    }
    int u = t - NL * 64 * 8;
    if (u >= 0 && u < NL * 2 * 4 * 64 * 8) {
        int e = u & 7, lane = (u >> 3) & 63, nt = (u >> 9) & 3, ks = (u >> 11) & 1, l = u >> 12;
        int k = ks * 32 + ((lane >> 4) << 3) + e;
        int col = nt * 16 + (lane & 15);
        w2f[u] = (_Float16)w2[l * 4096 + k * 64 + col];
    }
    int v = t - NL * 64 * 8 - NL * 2 * 4 * 64 * 8;
    if (v >= 0 && v < NL * 2 * 10 * 64 * 8) {
        int q = v / 5120, rem = v % 5120;
        int l = q >> 1, ks = q & 1;
        int nt = rem >> 9, lane = (rem >> 3) & 63, e = rem & 7;
        int k = ks * 32 + ((lane >> 4) << 3) + e;
        int col = nt * 16 + (lane & 15);
        w3f[v] = (_Float16)w3[l * 10240 + k * 160 + col];
    }
}

// ---------------------------------------------------------------- node init (packed record)
__global__ void init_kernel(const int* __restrict__ specie,
                            const float* __restrict__ emb,
                            _Float16* __restrict__ sv4) {
    int t = blockIdx.x * blockDim.x + threadIdx.x;
    if (t >= NNODES * NC) return;
    int n = t >> 5;
    int c = t & 31;
    half4v rec;
    rec[0] = (_Float16)0.f;
    rec[1] = (_Float16)0.f;
    rec[2] = (_Float16)0.f;
    rec[3] = (_Float16)emb[specie[n] * NC + c];
    *(half4v*)(sv4 + (size_t)n * 128 + c * 4) = rec;
}

// ---------------------------------------------------------------- MFMA radial MLP
__global__ __launch_bounds__(256) void mlpm_kernel(
    const float* __restrict__ rb_perm,     // [E][8] permuted order
    const float* __restrict__ w1t,         // [64][8] f32
    const _Float16* __restrict__ w2f,      // [2][4][64][8]
    const _Float16* __restrict__ w3f,      // [2][10][64][8]
    _Float16* __restrict__ wgt16)          // gather-friendly layout
{
    __shared__ float w1lds[512];
    __shared__ __align__(16) _Float16 lds2[4][2688];  // per-wave: h2 tile (stride 72) then out tile [16][168]

    for (int t = threadIdx.x; t < 512; t += 256) w1lds[t] = w1t[t];
    __syncthreads();

    int lane = threadIdx.x & 63;
    int wid  = threadIdx.x >> 6;
    int c16 = lane & 15;
    int kg  = lane >> 4;
    int ibase = blockIdx.x * 64 + wid * 16;
    int g = blockIdx.x * 4 + wid;

    // ---- h1 (VALU): 16 values per lane, directly in A-frag layout
    float4 ra4 = *(const float4*)(rb_perm + (size_t)(ibase + c16) * 8);
    float4 rb4 = *(const float4*)(rb_perm + (size_t)(ibase + c16) * 8 + 4);

    half8v a0, a1;
    #pragma unroll
    for (int e = 0; e < 8; ++e) {
        const float* wr0 = w1lds + (kg * 8 + e) * 8;
        float d0;
        d0 = ra4.x * wr0[0];
        d0 = fmaf(ra4.y, wr0[1], d0);
        d0 = fmaf(ra4.z, wr0[2], d0);
        d0 = fmaf(ra4.w, wr0[3], d0);
        d0 = fmaf(rb4.x, wr0[4], d0);
        d0 = fmaf(rb4.y, wr0[5], d0);
        d0 = fmaf(rb4.z, wr0[6], d0);
        d0 = fmaf(rb4.w, wr0[7], d0);
        a0[e] = (_Float16)silu_f(d0);
        const float* wr1 = w1lds + (32 + kg * 8 + e) * 8;
        float d1;
        d1 = ra4.x * wr1[0];
        d1 = fmaf(ra4.y, wr1[1], d1);
        d1 = fmaf(ra4.z, wr1[2], d1);
        d1 = fmaf(ra4.w, wr1[3], d1);
        d1 = fmaf(rb4.x, wr1[4], d1);
        d1 = fmaf(rb4.y, wr1[5], d1);
        d1 = fmaf(rb4.z, wr1[6], d1);
        d1 = fmaf(rb4.w, wr1[7], d1);
        a1[e] = (_Float16)silu_f(d1);
    }

    // ---- h2 via W2 MFMA (M=16 edges, N=64, K=64); staged at stride 72
    _Float16* tw = &lds2[wid][0];
    float4v zero4 = {0.f, 0.f, 0.f, 0.f};
    #pragma unroll
    for (int nt = 0; nt < 4; ++nt) {
        half8v b0 = *(const half8v*)(w2f + (size_t)(nt) * 512 + lane * 8);
        half8v b1 = *(const half8v*)(w2f + (size_t)(4 + nt) * 512 + lane * 8);
        float4v acc = __builtin_amdgcn_mfma_f32_16x16x32_f16(a0, b0, zero4, 0, 0, 0);
        acc = __builtin_amdgcn_mfma_f32_16x16x32_f16(a1, b1, acc, 0, 0, 0);
        #pragma unroll
        for (int r = 0; r < 4; ++r)
            tw[(kg * 4 + r) * 72 + nt * 16 + c16] = (_Float16)silu_f(acc[r]);
    }

    // re-read h2 as A-frags (row = c16, k = ks*32 + kg*8 + e)
    half8v a2 = *(const half8v*)(tw + c16 * 72 + kg * 8);
    half8v a3 = *(const half8v*)(tw + c16 * 72 + 32 + kg * 8);

    // ---- wgt via W3 MFMA (N=160); stage into pair layout [16 edges][168]
    #pragma unroll
    for (int nt = 0; nt < 10; ++nt) {
        half8v b0 = *(const half8v*)(w3f + (size_t)(nt) * 512 + lane * 8);
        half8v b1 = *(const half8v*)(w3f + (size_t)(10 + nt) * 512 + lane * 8);
        float4v acc = __builtin_amdgcn_mfma_f32_16x16x32_f16(a2, b0, zero4, 0, 0, 0);
        acc = __builtin_amdgcn_mfma_f32_16x16x32_f16(a3, b1, acc, 0, 0, 0);
        int slot;
        if (nt < 4)      slot = nt * 32 + 2 * c16;             // h = nt*16+c16 < 64  -> 2h
        else if (nt < 8) slot = (nt - 4) * 32 + 2 * c16 + 1;   // 64..127 -> 2(h-64)+1
        else             slot = 128 + (nt - 8) * 16 + c16;     // 128..159 -> h
        #pragma unroll
        for (int r = 0; r < 4; ++r)
            tw[(kg * 4 + r) * 168 + slot] = (_Float16)acc[r];
    }

    // coalesced copy: 16 edges x 160 f16 (2560 f16 = 320 uint4) -> global
    _Float16* gout = wgt16 + (size_t)g * 2560;
    #pragma unroll
    for (int u = 0; u < 5; ++u) {
        int g4 = u * 64 + lane;        // 0..319
        int edge = g4 / 20;
        int part = g4 % 20;
        half8v vv = *(const half8v*)(tw + edge * 168 + part * 8);
        *(half8v*)(gout + edge * 160 + part * 8) = vv;
    }
}

// ---------------------------------------------------------------- gather + TP (packed features)
__global__ __launch_bounds__(512) void gather_tp_kernel(
    const _Float16* __restrict__ wgt16,   // pair layout
    const float* __restrict__ nh_perm,    // [E][4]
    const int* __restrict__ snd_perm,     // [E]
    const int* __restrict__ rowstart, const int* __restrict__ deg,
    const _Float16* __restrict__ sv4,     // [N][32][4]
    _Float16* __restrict__ agg_s,   // [N][64]
    _Float16* __restrict__ agg_v)   // [N][96][3]
{
    int lane = threadIdx.x & 63;
    int wid  = threadIdx.x >> 6;
    int n = blockIdx.x * 8 + wid;
    if (n >= NNODES) return;

    int c = lane & 31;
    int half = lane >> 5;

    float accS = 0.f;
    float aVa0 = 0.f, aVa1 = 0.f, aVa2 = 0.f;   // half0: path2, half1: path3
    float aVb0 = 0.f, aVb1 = 0.f, aVb2 = 0.f;   // half0: path4, half1: garbage

    int start = rowstart[n];
    int cnt   = deg[n];

    // pipeline registers for edge i (loaded one iteration ahead)
    float4 nh_c = make_float4(0.f, 0.f, 0.f, 0.f);
    float d0_c = 0.f, d1_c = 0.f, d2_c = 0.f;
    float su_c = 0.f, v0_c = 0.f, v1_c = 0.f, v2_c = 0.f;
    if (cnt > 0) {
        int snd0 = snd_perm[start];
        nh_c = *(const float4*)(nh_perm + (size_t)start * 4);
        size_t gb = (size_t)(start >> 4) * 2560 + (size_t)(start & 15) * 160;
        half2v pr = u2h(*(const uint32*)(wgt16 + gb + lane * 2));
        d0_c = (float)pr.x;
        d1_c = (float)pr.y;
        d2_c = (float)wgt16[gb + 128 + c];
        half4v rec = *(const half4v*)(sv4 + (size_t)snd0 * 128 + c * 4);
        v0_c = (float)rec[0];
        v1_c = (float)rec[1];
        v2_c = (float)rec[2];
        su_c = (float)rec[3];
    }

    for (int i = 0; i < cnt; ++i) {
        float4 nh = nh_c;
        float d0 = d0_c, d1 = d1_c, d2f = d2_c;
        float su = su_c, v0 = v0_c, v1 = v1_c, v2 = v2_c;

        if (i + 1 < cnt) {
            int idx1 = start + i + 1;
            int snd1 = snd_perm[idx1];
            nh_c = *(const float4*)(nh_perm + (size_t)idx1 * 4);
            size_t gb1 = (size_t)(idx1 >> 4) * 2560 + (size_t)(idx1 & 15) * 160;
            half2v pr1 = u2h(*(const uint32*)(wgt16 + gb1 + lane * 2));
            d0_c = (float)pr1.x;
            d1_c = (float)pr1.y;
            d2_c = (float)wgt16[gb1 + 128 + c];
            half4v rec1 = *(const half4v*)(sv4 + (size_t)snd1 * 128 + c * 4);
            v0_c = (float)rec1[0];
            v1_c = (float)rec1[1];
            v2_c = (float)rec1[2];
            su_c = (float)rec1[3];
        }

        float ndv = nh.x * v0;
        ndv = fmaf(nh.y, v1, ndv);
        ndv = fmaf(nh.z, v2, ndv);

        float sSel = half ? ndv : su;          // path1 vs path0 multiplier
        accS = fmaf(d0, sSel, accS);
        float scale = half ? d1 : d1 * su;     // path3: w3 ; path2: w2*su
        float f0 = half ? v0 : nh.x;
        float f1 = half ? v1 : nh.y;
        float f2 = half ? v2 : nh.z;
        aVa0 = fmaf(scale, f0, aVa0);
        aVa1 = fmaf(scale, f1, aVa1);
        aVa2 = fmaf(scale, f2, aVa2);
        float m4 = half ? 0.f : d2f;           // path4 only on half0
        aVb0 = fmaf(m4, fmaf(nh.x, ndv, -v0 * (1.f / 3.f)), aVb0);
        aVb1 = fmaf(m4, fmaf(nh.y, ndv, -v1 * (1.f / 3.f)), aVb1);
        aVb2 = fmaf(m4, fmaf(nh.z, ndv, -v2 * (1.f / 3.f)), aVb2);
    }

    agg_s[(size_t)n * 64 + lane] = (_Float16)accS;
    _Float16* av = agg_v + (size_t)n * 288;
    if (half == 0) {
        av[c * 3 + 0] = (_Float16)aVa0; av[c * 3 + 1] = (_Float16)aVa1; av[c * 3 + 2] = (_Float16)aVa2;                      // path2
        av[(64 + c) * 3 + 0] = (_Float16)aVb0; av[(64 + c) * 3 + 1] = (_Float16)aVb1; av[(64 + c) * 3 + 2] = (_Float16)aVb2; // path4
    } else {
        av[(32 + c) * 3 + 0] = (_Float16)aVa0; av[(32 + c) * 3 + 1] = (_Float16)aVa1; av[(32 + c) * 3 + 2] = (_Float16)aVa2; // path3
    }
}

// ---------------------------------------------------------------- node update (packed features)
__global__ __launch_bounds__(256) void node_kernel(
    const int* __restrict__ specie,
    const _Float16* __restrict__ agg_s, const _Float16* __restrict__ agg_v,
    const _Float16* __restrict__ sv4_in,
    const float* __restrict__ wls,   // [64][64]
    const float* __restrict__ wlv,   // [96][32]
    const float* __restrict__ wscs,  // [5][32][64]
    const float* __restrict__ wscv,  // [5][32][32]
    _Float16* __restrict__ sv4_out)
{
    __shared__ float sAV[4][288];
    __shared__ float sVO[4][96];

    int lane = threadIdx.x & 63;
    int wid  = threadIdx.x >> 6;
    int n = blockIdx.x * 4 + wid;
    if (n >= NNODES) return;
    int sp = specie[n];
    int c = lane & 31;
    int h = lane >> 5;

    const _Float16* av = agg_v + (size_t)n * 288;
    sAV[wid][lane]       = (float)av[lane];
    sAV[wid][64 + lane]  = (float)av[64 + lane];
    sAV[wid][128 + lane] = (float)av[128 + lane];
    sAV[wid][192 + lane] = (float)av[192 + lane];
    if (lane < 32) sAV[wid][256 + lane] = (float)av[256 + lane];

    half4v rec = *(const half4v*)(sv4_in + (size_t)n * 128 + c * 4);
    float sv = (float)rec[3];
    if (lane < 32) {
        sVO[wid][lane]      = (float)rec[0];
        sVO[wid][32 + lane] = (float)rec[1];
        sVO[wid][64 + lane] = (float)rec[2];
    }

    float asv = (float)agg_s[(size_t)n * 64 + lane];

    __syncthreads();

    float sg = 0.f;
    #pragma unroll
    for (int j = 0; j < 64; ++j)
        sg = fmaf(rdlane(asv, j), wls[j * 64 + lane], sg);
    sg *= INV_AVG;
    const float* ws = wscs + (size_t)sp * 32 * 64;
    #pragma unroll
    for (int j = 0; j < 32; ++j)
        sg = fmaf(rdlane(sv, j), ws[j * 64 + lane], sg);
    float act  = silu_f(sg);
    float gate = __shfl(act, c + 32);

    float vn1 = 0.f, vn2 = 0.f;
    #pragma unroll
    for (int p = 0; p < 96; ++p) {
        float w = wlv[p * 32 + c];
        vn1 = fmaf(sAV[wid][3 * p + h], w, vn1);
        vn2 = fmaf(sAV[wid][3 * p + 2], w, vn2);
    }
    vn1 *= INV_AVG; vn2 *= INV_AVG;
    const float* wv = wscv + (size_t)sp * 32 * 32;
    #pragma unroll
    for (int j = 0; j < 32; ++j) {
        float w = wv[j * 32 + c];
        vn1 = fmaf(sVO[wid][h * 32 + j], w, vn1);
        vn2 = fmaf(sVO[wid][64 + j],     w, vn2);
    }

    float vd = gate * vn1;                 // half0: d0, half1: d1
    float d1v = __shfl(vd, c + 32);        // d1 value onto half0 lanes
    if (lane < 32) {
        half4v o;
        o[0] = (_Float16)vd;               // d0
        o[1] = (_Float16)d1v;              // d1
        o[2] = (_Float16)(gate * vn2);     // d2
        o[3] = (_Float16)act;              // s
        *(half4v*)(sv4_out + (size_t)n * 128 + lane * 4) = o;
    }
}

// ---------------------------------------------------------------- output head
__global__ void out_kernel(const _Float16* __restrict__ sv4,
                           const float* __restrict__ w1,  // [32][16]
                           const float* __restrict__ w2,  // [16][1]
                           float* __restrict__ out) {
    int n = blockIdx.x * blockDim.x + threadIdx.x;
    if (n >= NNODES) return;
    float sv[NC];
    #pragma unroll
    for (int c = 0; c < NC; ++c) sv[c] = (float)sv4[(size_t)n * 128 + c * 4 + 3];
    float e = 0.f;
    #pragma unroll
    for (int j = 0; j < 16; ++j) {
        float tj = 0.f;
        #pragma unroll
        for (int c = 0; c < NC; ++c) tj += sv[c] * w1[c * 16 + j];
        e += tj * w2[j];
    }
    out[n] = e;
}

// ---------------------------------------------------------------- launcher
extern "C" void kernel_launch(void* const* d_in, const int* in_sizes, int n_in,
                              void* d_out, int out_size, void* d_ws, size_t ws_size,
                              hipStream_t stream) {
    const float* vectors   = (const float*)d_in[0];
    const int*   specie    = (const int*)  d_in[1];
    const int*   senders   = (const int*)  d_in[2];
    const int*   receivers = (const int*)  d_in[3];
    const float* emb       = (const float*)d_in[4];
    const float* w_rad1    = (const float*)d_in[5];
    const float* w_rad2    = (const float*)d_in[6];
    const float* w_rad_out = (const float*)d_in[7];
    const float* w_lin_s   = (const float*)d_in[8];
    const float* w_lin_v   = (const float*)d_in[9];
    const float* w_sc_s    = (const float*)d_in[10];
    const float* w_sc_v    = (const float*)d_in[11];
    const float* w_out1    = (const float*)d_in[12];
    const float* w_out2    = (const float*)d_in[13];

    char* base = (char*)d_ws;
    size_t off = 0;
    auto alloc = [&](size_t bytes) { char* q = base + off; off += (bytes + 255) & ~(size_t)255; return q; };

    float*    nh_perm  = (float*)alloc((size_t)NEDGES * 4 * 4);
    float*    rb_perm  = (float*)alloc((size_t)NEDGES * 8 * 4);
    int*      snd_perm = (int*)alloc((size_t)NEDGES * 4);
    int*      epos     = (int*)alloc((size_t)NEDGES * 4);
    _Float16* sv4_a    = (_Float16*)alloc((size_t)NNODES * 128 * 2);
    _Float16* sv4_b    = (_Float16*)alloc((size_t)NNODES * 128 * 2);
    _Float16* aggs     = (_Float16*)alloc((size_t)NNODES * 2 * NC * 2);
    _Float16* aggv     = (_Float16*)alloc((size_t)NNODES * 3 * NC * 3 * 2);
    int* deg        = (int*)alloc((size_t)NNODES * 4);
    int* rowstart   = (int*)alloc((size_t)(NNODES + 4) * 4);
    float*    w1t      = (float*)alloc((size_t)NL * 64 * 8 * 4);
    _Float16* w2f      = (_Float16*)alloc((size_t)NL * 2 * 4 * 64 * 8 * 2);
    _Float16* w3f      = (_Float16*)alloc((size_t)NL * 2 * 10 * 64 * 8 * 2);
    _Float16* wgt16    = (_Float16*)alloc((size_t)NEDGES * 160 * 2);
    if (off > ws_size) return;   // workspace too small (should not happen; ~220 MB)

    // CSR + permuted geometry (once; graph static across layers)
    (void)hipMemsetAsync(deg, 0, NNODES * sizeof(int), stream);
    fill_kernel<<<(NEDGES + 255) / 256, 256, 0, stream>>>(receivers, deg, epos);
    scan_kernel<<<1, 256, 0, stream>>>(deg, rowstart);
    geom_perm_kernel<<<(NEDGES + 255) / 256, 256, 0, stream>>>(
        vectors, senders, receivers, rowstart, epos, nh_perm, snd_perm, rb_perm);
    int prep_n = NL * 64 * 8 + NL * 2 * 4 * 64 * 8 + NL * 2 * 10 * 64 * 8;
    prepw_kernel<<<(prep_n + 255) / 256, 256, 0, stream>>>(
        w_rad1, w_rad2, w_rad_out, w1t, w2f, w3f);

    init_kernel<<<(NNODES * NC + 255) / 256, 256, 0, stream>>>(specie, emb, sv4_a);

    _Float16* si = sv4_a; _Float16* so = sv4_b;
    for (int l = 0; l < NL; ++l) {
        mlpm_kernel<<<NEDGES / 64, 256, 0, stream>>>(
            rb_perm,
            w1t + (size_t)l * 512,
            w2f + (size_t)l * 4096,
            w3f + (size_t)l * 10240,
            wgt16);
        gather_tp_kernel<<<(NNODES + 7) / 8, 512, 0, stream>>>(
            wgt16, nh_perm, snd_perm, rowstart, deg, si, aggs, aggv);
        node_kernel<<<(NNODES + 3) / 4, 256, 0, stream>>>(
            specie, aggs, aggv, si,
            w_lin_s + (size_t)l * 64 * 64,
            w_lin_v + (size_t)l * 96 * 32,
            w_sc_s + (size_t)l * NSPEC * NC * 64,
            w_sc_v + (size_t)l * NSPEC * NC * NC,
            so);
        _Float16* ts = si; si = so; so = ts;
    }

    out_kernel<<<(NNODES + 255) / 256, 256, 0, stream>>>(si, w_out1, w_out2, (float*)d_out);
}